// Round 16
// baseline (35.967 us; speedup 1.0000x reference)
//
#include <hip/hip_runtime.h>
#include <hip/hip_bf16.h>

// GNN layer: out = (A @ x) @ W^T + bias,  A = fixed 8-neighbor stencil.
// x[64][65536] f32, W[256][65536] f32, bias[256], out[64][256] f32.
// R16: R10 fused structure, k-split to 512 blocks (KSP 128) with
// __launch_bounds__(1024,8) -> 2 blocks/CU co-resident so the x/stencil
// phase of one block overlaps the W/MFMA phase of the other.

#define MB    64
#define NOUT  256
#define KDIM  65536
#define NTOT  (MB * KDIM)
#define KSP   128               // k-span per block
#define NCH   (KDIM / KSP)      // 512 blocks
#define OTOT  (MB * NOUT)       // 16384
#define LSTR  136               // h1 LDS row stride (ushorts)

typedef __attribute__((ext_vector_type(8))) short bf16x8;
typedef __attribute__((ext_vector_type(8))) unsigned short ushort8v;
typedef __attribute__((ext_vector_type(4))) float f32x4;

__device__ __forceinline__ ushort f2bf(float f) {
    __hip_bfloat16 h = __float2bfloat16(f);
    return *reinterpret_cast<ushort*>(&h);
}
__device__ __forceinline__ float bf2f(ushort u) {
    return __uint_as_float((unsigned)u << 16);
}

// ---------------------------------------------------------------------------
// Stencil: 8 bf16 h1 values at flat index g.  h1[b,i] = x[b,i] +
// sum_o ([center(i)]+[center(i+o)])*x[b,i+o]; centers = flat 257..65278
// (matches reference COO). Clamped OOB loads only feed weight-0 terms.
// ---------------------------------------------------------------------------
__device__ __forceinline__ ushort8v stencil8v(const float* __restrict__ x, int g) {
    const int i8 = g & (KDIM - 1);
    union Span { float4 v[4]; float f[16]; };
    Span u, c, d;
    #pragma unroll
    for (int q = 0; q < 4; ++q) {
        int bu = g - 260 + 4 * q; if (bu < 0) bu = 0;
        int bc = g - 4   + 4 * q; if (bc < 0) bc = 0; if (bc > NTOT - 4) bc = NTOT - 4;
        int bd = g + 252 + 4 * q; if (bd > NTOT - 4) bd = NTOT - 4;
        u.v[q] = *(const float4*)(x + bu);
        c.v[q] = *(const float4*)(x + bc);
        d.v[q] = *(const float4*)(x + bd);
    }
    ushort8v ov;
    if (i8 >= 520 && i8 <= 65008) {          // fast path: everything interior
        #pragma unroll
        for (int e = 0; e < 8; ++e) {
            float nb = c.f[3 + e] + c.f[5 + e]
                     + u.f[3 + e] + u.f[4 + e] + u.f[5 + e]
                     + d.f[3 + e] + d.f[4 + e] + d.f[5 + e];
            ov[e] = (short)f2bf(fmaf(2.0f, nb, c.f[4 + e]));
        }
    } else {
        #pragma unroll
        for (int e = 0; e < 8; ++e) {
            const int ii = i8 + e;
            const float ci = ((unsigned)(ii - 257) <= (65278u - 257u)) ? 1.0f : 0.0f;
            float s = c.f[4 + e];
            const int   doff[8] = {-1, 1, -257, -256, -255, 255, 256, 257};
            const float* src[8] = {&c.f[3 + e], &c.f[5 + e],
                                   &u.f[3 + e], &u.f[4 + e], &u.f[5 + e],
                                   &d.f[3 + e], &d.f[4 + e], &d.f[5 + e]};
            #pragma unroll
            for (int t = 0; t < 8; ++t) {
                const int j = ii + doff[t];
                const float cj = ((unsigned)(j - 257) <= (65278u - 257u)) ? 1.0f : 0.0f;
                s = fmaf(ci + cj, *src[t], s);
            }
            ov[e] = (short)f2bf(s);
        }
    }
    return ov;
}

// ---------------------------------------------------------------------------
// FUSED kernel. Block = k-chunk kp (512 blocks, target 2/CU). 1024 threads.
// Phase A: h1 slice [64 m][128 k] -> LDS bf16 (8 elems/thread).
// Phase B: wave = n-tile nt (16 waves); W plain loads (compiler-scheduled,
//          R10-proven); 4 k-steps x 4 m-tiles MFMA.
// bf16 partial [kp][n][m]. XCD-chunk: kp = (b%8)*64 + b/8.
// ---------------------------------------------------------------------------
__global__ __launch_bounds__(1024, 8) void fused_sg(const float* __restrict__ x,
                                                    const float* __restrict__ W,
                                                    ushort* __restrict__ part) {
    __shared__ ushort hs[MB * LSTR];     // 17408 B
    const int b  = blockIdx.x;
    const int kp = (b & 7) * 64 + (b >> 3);      // 0..511
    const int t  = threadIdx.x;

    // ---- Phase A: stencil (8 elems/thread) ----
    {
        const int m = t >> 4;                    // 0..63
        const int j = t & 15;                    // k-offset j*8
        const int g = m * KDIM + kp * KSP + j * 8;
        ushort8v o0 = stencil8v(x, g);
        *(ushort8v*)&hs[m * LSTR + j * 8] = o0;
    }
    __syncthreads();

    // ---- Phase B: MFMA gemm ----
    const int nt = t >> 6;                       // 0..15 n-tile
    const int l  = t & 63;
    const int lr = l & 15;
    const int lg = l >> 4;

    f32x4 acc0 = (f32x4){0.f,0.f,0.f,0.f}, acc1 = (f32x4){0.f,0.f,0.f,0.f};
    f32x4 acc2 = (f32x4){0.f,0.f,0.f,0.f}, acc3 = (f32x4){0.f,0.f,0.f,0.f};

    const float* wp = W + (size_t)(nt * 16 + lr) * KDIM + kp * KSP + lg * 8;

    #pragma unroll
    for (int ks = 0; ks < KSP / 32; ++ks) {      // 4 fully-unrolled steps
        float4 w0 = *(const float4*)(wp + ks * 32);
        float4 w1 = *(const float4*)(wp + ks * 32 + 4);
        union { ushort u[8]; bf16x8 v; } bb;
        bb.u[0] = f2bf(w0.x); bb.u[1] = f2bf(w0.y);
        bb.u[2] = f2bf(w0.z); bb.u[3] = f2bf(w0.w);
        bb.u[4] = f2bf(w1.x); bb.u[5] = f2bf(w1.y);
        bb.u[6] = f2bf(w1.z); bb.u[7] = f2bf(w1.w);
        bf16x8 af0 = *(const bf16x8*)&hs[(0 * 16 + lr) * LSTR + lg * 8 + ks * 32];
        bf16x8 af1 = *(const bf16x8*)&hs[(1 * 16 + lr) * LSTR + lg * 8 + ks * 32];
        bf16x8 af2 = *(const bf16x8*)&hs[(2 * 16 + lr) * LSTR + lg * 8 + ks * 32];
        bf16x8 af3 = *(const bf16x8*)&hs[(3 * 16 + lr) * LSTR + lg * 8 + ks * 32];
        acc0 = __builtin_amdgcn_mfma_f32_16x16x32_bf16(af0, bb.v, acc0, 0, 0, 0);
        acc1 = __builtin_amdgcn_mfma_f32_16x16x32_bf16(af1, bb.v, acc1, 0, 0, 0);
        acc2 = __builtin_amdgcn_mfma_f32_16x16x32_bf16(af2, bb.v, acc2, 0, 0, 0);
        acc3 = __builtin_amdgcn_mfma_f32_16x16x32_bf16(af3, bb.v, acc3, 0, 0, 0);
    }

    // D layout: n-col = lane&15, m = (lane>>4)*4 + reg (m89/m91-verified).
    // part[kp][n][m]: lane's 4 m consecutive -> ushort4 stores.
    ushort* pb = part + (size_t)kp * OTOT + (size_t)(nt * 16 + lr) * MB;
    ushort4 s;
    s.x = f2bf(acc0[0]); s.y = f2bf(acc0[1]); s.z = f2bf(acc0[2]); s.w = f2bf(acc0[3]);
    *(ushort4*)(pb + 0 * 16 + lg * 4) = s;
    s.x = f2bf(acc1[0]); s.y = f2bf(acc1[1]); s.z = f2bf(acc1[2]); s.w = f2bf(acc1[3]);
    *(ushort4*)(pb + 1 * 16 + lg * 4) = s;
    s.x = f2bf(acc2[0]); s.y = f2bf(acc2[1]); s.z = f2bf(acc2[2]); s.w = f2bf(acc2[3]);
    *(ushort4*)(pb + 2 * 16 + lg * 4) = s;
    s.x = f2bf(acc3[0]); s.y = f2bf(acc3[1]); s.z = f2bf(acc3[2]); s.w = f2bf(acc3[3]);
    *(ushort4*)(pb + 3 * 16 + lg * 4) = s;
}

// ---------------------------------------------------------------------------
// Reduce 512 bf16 partials (+bias) -> f32 out[64][256].
// 512 blocks x 256 thr: 8 threads/output, 64 chunks each, LDS combine.
// part[kc][n*64+m]; out[m][n].
// ---------------------------------------------------------------------------
__global__ __launch_bounds__(256) void reduce_bf16(const ushort* __restrict__ part,
                                                   const float* __restrict__ bias,
                                                   float* __restrict__ out) {
    __shared__ float red[256];
    const int ol = threadIdx.x & 31;
    const int cg = threadIdx.x >> 5;             // 0..7 -> 64 chunks each
    const int o  = blockIdx.x * 32 + ol;         // 0..16383
    const ushort* p = part + (size_t)cg * 64 * OTOT + o;
    float s0 = 0.f, s1 = 0.f, s2 = 0.f, s3 = 0.f;
    #pragma unroll 4
    for (int i = 0; i < 64; i += 4) {
        s0 += bf2f(p[(size_t)(i + 0) * OTOT]);
        s1 += bf2f(p[(size_t)(i + 1) * OTOT]);
        s2 += bf2f(p[(size_t)(i + 2) * OTOT]);
        s3 += bf2f(p[(size_t)(i + 3) * OTOT]);
    }
    red[threadIdx.x] = (s0 + s1) + (s2 + s3);
    __syncthreads();
    if (cg == 0) {
        float v = red[ol];
        #pragma unroll
        for (int jj = 1; jj < 8; ++jj) v += red[jj * 32 + ol];
        const int n = o >> 6, m = o & 63;
        out[m * NOUT + n] = v + bias[n];
    }
}

// ---------------------------------------------------------------------------
extern "C" void kernel_launch(void* const* d_in, const int* in_sizes, int n_in,
                              void* d_out, int out_size, void* d_ws, size_t ws_size,
                              hipStream_t stream) {
    const float* x    = (const float*)d_in[0];
    const float* W    = (const float*)d_in[1];
    const float* bias = (const float*)d_in[2];
    float* out = (float*)d_out;

    ushort* part = (ushort*)d_ws;                // 512*16384*2 = 16 MiB

    fused_sg<<<NCH, 1024, 0, stream>>>(x, W, part);
    reduce_bf16<<<OTOT / 32, 256, 0, stream>>>(part, bias, out);
}

// Round 17
// 35.054 us; speedup vs baseline: 1.0260x; 1.0260x over previous
//
#include <hip/hip_runtime.h>
#include <hip/hip_bf16.h>

// GNN layer: out = (A @ x) @ W^T + bias,  A = fixed 8-neighbor stencil.
// x[64][65536] f32, W[256][65536] f32, bias[256], out[64][256] f32.
// R17: R10 fused structure (proven best, 33.9us) with (1) merged 16-element
// stencil (18 float4 x-loads instead of 24) and (2) 16-thread/output reduce.

#define MB    64
#define NOUT  256
#define KDIM  65536
#define NTOT  (MB * KDIM)
#define KSP   256               // k-span per block
#define NCH   (KDIM / KSP)      // 256 blocks
#define OTOT  (MB * NOUT)       // 16384
#define LSTR  272               // h1 LDS row stride in ushorts (544 B)

typedef __attribute__((ext_vector_type(8))) short bf16x8;
typedef __attribute__((ext_vector_type(8))) unsigned short ushort8v;
typedef __attribute__((ext_vector_type(4))) float f32x4;

__device__ __forceinline__ ushort f2bf(float f) {
    __hip_bfloat16 h = __float2bfloat16(f);
    return *reinterpret_cast<ushort*>(&h);
}
__device__ __forceinline__ float bf2f(ushort u) {
    return __uint_as_float((unsigned)u << 16);
}

// ---------------------------------------------------------------------------
// Stencil: 16 bf16 h1 values at flat index g (multiple of 16).
// h1[b,i] = x[b,i] + sum_o ([center(i)]+[center(i+o)])*x[b,i+o];
// centers = flat 257..65278 (matches reference COO; offsets are FLAT with
// row wraparound, exactly as the reference builds them). Merged spans:
// 3 rows x 24 floats (6 float4 each) = 18 loads for 16 outputs.
// Clamped OOB loads only feed weight-0 terms.
// ---------------------------------------------------------------------------
__device__ __forceinline__ void stencil16v(const float* __restrict__ x, int g,
                                           ushort8v* o0, ushort8v* o1) {
    const int i8 = g & (KDIM - 1);
    union Span { float4 v[6]; float f[24]; };
    Span u, c, d;
    #pragma unroll
    for (int q = 0; q < 6; ++q) {
        int bu = g - 260 + 4 * q; if (bu < 0) bu = 0;
        int bc = g - 4   + 4 * q; if (bc < 0) bc = 0; if (bc > NTOT - 4) bc = NTOT - 4;
        int bd = g + 252 + 4 * q; if (bd > NTOT - 4) bd = NTOT - 4;
        u.v[q] = *(const float4*)(x + bu);
        c.v[q] = *(const float4*)(x + bc);
        d.v[q] = *(const float4*)(x + bd);
    }
    // element e: u-row vals at f[e+3..e+5], c-row at f[e+3],f[e+4],f[e+5],
    // d-row at f[e+3..e+5] (same indexing as the proven 8-elem version).
    if (i8 >= 514 && i8 <= 65006) {          // all 16 outputs fully interior
        #pragma unroll
        for (int e = 0; e < 16; ++e) {
            float nb = c.f[3 + e] + c.f[5 + e]
                     + u.f[3 + e] + u.f[4 + e] + u.f[5 + e]
                     + d.f[3 + e] + d.f[4 + e] + d.f[5 + e];
            const ushort o = f2bf(fmaf(2.0f, nb, c.f[4 + e]));
            if (e < 8) (*o0)[e] = o; else (*o1)[e - 8] = o;
        }
    } else {
        #pragma unroll
        for (int e = 0; e < 16; ++e) {
            const int ii = i8 + e;
            const float ci = ((unsigned)(ii - 257) <= (65278u - 257u)) ? 1.0f : 0.0f;
            float s = c.f[4 + e];
            const int   doff[8] = {-1, 1, -257, -256, -255, 255, 256, 257};
            const float* src[8] = {&c.f[3 + e], &c.f[5 + e],
                                   &u.f[3 + e], &u.f[4 + e], &u.f[5 + e],
                                   &d.f[3 + e], &d.f[4 + e], &d.f[5 + e]};
            #pragma unroll
            for (int t = 0; t < 8; ++t) {
                const int j = ii + doff[t];
                const float cj = ((unsigned)(j - 257) <= (65278u - 257u)) ? 1.0f : 0.0f;
                s = fmaf(ci + cj, *src[t], s);
            }
            const ushort o = f2bf(s);
            if (e < 8) (*o0)[e] = o; else (*o1)[e - 8] = o;
        }
    }
}

// ---------------------------------------------------------------------------
// FUSED kernel (R10 geometry). Block = k-chunk kp (256 blocks). 1024 threads.
// Phase A: h1 slice [64 m][256 k] -> LDS bf16 (stride 272), 16 elems/thread.
// Phase B: wave = n-tile nt (16 waves); W streamed f32->bf16 (compiler-
//          scheduled); 8 k-steps x 4 m-tiles MFMA.
// bf16 partial [kp][n][m]. XCD-chunk: kp = (b%8)*32 + b/8.
// ---------------------------------------------------------------------------
__global__ __launch_bounds__(1024, 4) void fused_sg(const float* __restrict__ x,
                                                    const float* __restrict__ W,
                                                    ushort* __restrict__ part) {
    __shared__ ushort hs[MB * LSTR];     // 34816 B
    const int b  = blockIdx.x;
    const int kp = (b & 7) * 32 + (b >> 3);      // 0..255
    const int t  = threadIdx.x;

    // ---- Phase A: stencil (16 elems/thread, merged spans) ----
    {
        const int m = t >> 4;                    // 0..63
        const int j = t & 15;                    // k-offset j*16
        const int g = m * KDIM + kp * KSP + j * 16;
        ushort8v o0, o1;
        stencil16v(x, g, &o0, &o1);
        *(ushort8v*)&hs[m * LSTR + j * 16]     = o0;
        *(ushort8v*)&hs[m * LSTR + j * 16 + 8] = o1;
    }
    __syncthreads();

    // ---- Phase B: MFMA gemm ----
    const int nt = t >> 6;                       // 0..15 n-tile
    const int l  = t & 63;
    const int lr = l & 15;
    const int lg = l >> 4;

    f32x4 acc0 = (f32x4){0.f,0.f,0.f,0.f}, acc1 = (f32x4){0.f,0.f,0.f,0.f};
    f32x4 acc2 = (f32x4){0.f,0.f,0.f,0.f}, acc3 = (f32x4){0.f,0.f,0.f,0.f};

    const float* wp = W + (size_t)(nt * 16 + lr) * KDIM + kp * KSP + lg * 8;

    #pragma unroll
    for (int ks = 0; ks < KSP / 32; ++ks) {      // 8 fully-unrolled steps
        float4 w0 = *(const float4*)(wp + ks * 32);
        float4 w1 = *(const float4*)(wp + ks * 32 + 4);
        union { ushort u[8]; bf16x8 v; } bb;
        bb.u[0] = f2bf(w0.x); bb.u[1] = f2bf(w0.y);
        bb.u[2] = f2bf(w0.z); bb.u[3] = f2bf(w0.w);
        bb.u[4] = f2bf(w1.x); bb.u[5] = f2bf(w1.y);
        bb.u[6] = f2bf(w1.z); bb.u[7] = f2bf(w1.w);
        bf16x8 af0 = *(const bf16x8*)&hs[(0 * 16 + lr) * LSTR + lg * 8 + ks * 32];
        bf16x8 af1 = *(const bf16x8*)&hs[(1 * 16 + lr) * LSTR + lg * 8 + ks * 32];
        bf16x8 af2 = *(const bf16x8*)&hs[(2 * 16 + lr) * LSTR + lg * 8 + ks * 32];
        bf16x8 af3 = *(const bf16x8*)&hs[(3 * 16 + lr) * LSTR + lg * 8 + ks * 32];
        acc0 = __builtin_amdgcn_mfma_f32_16x16x32_bf16(af0, bb.v, acc0, 0, 0, 0);
        acc1 = __builtin_amdgcn_mfma_f32_16x16x32_bf16(af1, bb.v, acc1, 0, 0, 0);
        acc2 = __builtin_amdgcn_mfma_f32_16x16x32_bf16(af2, bb.v, acc2, 0, 0, 0);
        acc3 = __builtin_amdgcn_mfma_f32_16x16x32_bf16(af3, bb.v, acc3, 0, 0, 0);
    }

    // D layout: n-col = lane&15, m = (lane>>4)*4 + reg (m89/m91-verified).
    // part[kp][n][m]: lane's 4 m consecutive -> ushort4 stores.
    ushort* pb = part + (size_t)kp * OTOT + (size_t)(nt * 16 + lr) * MB;
    ushort4 s;
    s.x = f2bf(acc0[0]); s.y = f2bf(acc0[1]); s.z = f2bf(acc0[2]); s.w = f2bf(acc0[3]);
    *(ushort4*)(pb + 0 * 16 + lg * 4) = s;
    s.x = f2bf(acc1[0]); s.y = f2bf(acc1[1]); s.z = f2bf(acc1[2]); s.w = f2bf(acc1[3]);
    *(ushort4*)(pb + 1 * 16 + lg * 4) = s;
    s.x = f2bf(acc2[0]); s.y = f2bf(acc2[1]); s.z = f2bf(acc2[2]); s.w = f2bf(acc2[3]);
    *(ushort4*)(pb + 2 * 16 + lg * 4) = s;
    s.x = f2bf(acc3[0]); s.y = f2bf(acc3[1]); s.z = f2bf(acc3[2]); s.w = f2bf(acc3[3]);
    *(ushort4*)(pb + 3 * 16 + lg * 4) = s;
}

// ---------------------------------------------------------------------------
// Reduce 256 bf16 partials (+bias) -> f32 out[64][256].
// 1024 blocks x 256 thr: 16 threads/output, 16 chunks each, LDS combine.
// part[kc][n*64+m]; out[m][n].
// ---------------------------------------------------------------------------
__global__ __launch_bounds__(256) void reduce_bf16(const ushort* __restrict__ part,
                                                   const float* __restrict__ bias,
                                                   float* __restrict__ out) {
    __shared__ float red[256];
    const int ol = threadIdx.x & 15;             // output lane (16/block)
    const int cg = threadIdx.x >> 4;             // 0..15 -> 16 chunks each
    const int o  = blockIdx.x * 16 + ol;         // 0..16383
    const ushort* p = part + (size_t)cg * 16 * OTOT + o;
    float s0 = 0.f, s1 = 0.f, s2 = 0.f, s3 = 0.f;
    #pragma unroll
    for (int i = 0; i < 16; i += 4) {
        s0 += bf2f(p[(size_t)(i + 0) * OTOT]);
        s1 += bf2f(p[(size_t)(i + 1) * OTOT]);
        s2 += bf2f(p[(size_t)(i + 2) * OTOT]);
        s3 += bf2f(p[(size_t)(i + 3) * OTOT]);
    }
    red[threadIdx.x] = (s0 + s1) + (s2 + s3);
    __syncthreads();
    if (cg == 0) {
        float v = red[ol];
        #pragma unroll
        for (int jj = 1; jj < 16; ++jj) v += red[jj * 16 + ol];
        const int n = o >> 6, m = o & 63;
        out[m * NOUT + n] = v + bias[n];
    }
}

// ---------------------------------------------------------------------------
extern "C" void kernel_launch(void* const* d_in, const int* in_sizes, int n_in,
                              void* d_out, int out_size, void* d_ws, size_t ws_size,
                              hipStream_t stream) {
    const float* x    = (const float*)d_in[0];
    const float* W    = (const float*)d_in[1];
    const float* bias = (const float*)d_in[2];
    float* out = (float*)d_out;

    ushort* part = (ushort*)d_ws;                // 256*16384*2 = 8 MiB

    fused_sg<<<NCH, 1024, 0, stream>>>(x, W, part);
    reduce_bf16<<<OTOT / 16, 256, 0, stream>>>(part, bias, out);
}